// Round 10
// baseline (1196.447 us; speedup 1.0000x reference)
//
#include <hip/hip_runtime.h>
#include <hip/hip_bf16.h>

// SentenceEmbedding: 3 parallel BiLSTM branches + time maxpool.
// B=256, T=128, E=256, H=256, 4H=1024. Output [256][1536] f32.
//
// R7: barrier-free dual-chain WGs.
//  - 96 WGs = layer(3) x cg(8) x bg(4); 512 thr = 8 waves: dir = wv>>2 (fwd/bwd
//    chains in one WG -> 2 waves/SIMD of independent recurrences hide each
//    other's exchange stalls), mq = wv&3 (8 h-dims per wave).
//  - Per wave: M=32 gate-cols (mq), N=64 batch. uf = 64 VGPRs, W in LDS
//    (128 KB, no duplicated reads). NO __syncthreads in the loop.
//  - Publish: self-contained per-wave slice (8hd x 64b), 8 scattered 2B
//    relaxed-atomic stores -> vmcnt(0) -> per-WAVE tag.
//  - Poll: only mq0 wave polls the 32 sibling tags (one 128B line); mq1-3
//    spin on an LDS flag (no L3 traffic).

#define NB 256
#define NT 128
#define NE 256
#define NH 256
#define NG 1024

using bf16x8 = __attribute__((ext_vector_type(8))) short;
using f32x4  = __attribute__((ext_vector_type(4))) float;
typedef unsigned long long u64;

// ws layout (bytes)
#define X_OFF   0u           // 16 MB  x2: B-frag order [t][bg][kt][nt][lane][8]
#define WT_OFF  16777216u    // 3 MB   W^T A-frag pack
#define UT_OFF  19922944u    // 3 MB   U^T A-frag pack
#define HB_OFF  23068672u    // 1.5 MB h exchange (2 par x 24 grp x 8 cg x 4 mq x 1KB)
#define TAG_OFF 24641536u    // 3 KB   tags[24][32] u32 (128B line per group)
#define HB_PAR_U64 98304     // u64 per parity
#define HB_PAR_US  393216    // ushort per parity

static __device__ __forceinline__ ushort f2bf(float f) {
  union { float f; unsigned u; } v; v.f = f;
  unsigned r = v.u + 0x7fffu + ((v.u >> 16) & 1u);   // RNE
  return (ushort)(r >> 16);
}
static __device__ __forceinline__ float rcp_(float x) { return __builtin_amdgcn_rcpf(x); }
static __device__ __forceinline__ float sigf(float x) { return rcp_(1.f + __expf(-x)); }
static __device__ __forceinline__ float tanhf_(float x) { return 1.f - 2.f * rcp_(__expf(2.f * x) + 1.f); }

// ---------------- embed directly into B-frag order ----------------
// x2 slot tid holds x[b][e0..e0+7], b = bg*64+nt*16+(lane&15), e0 = kt*32+(lane>>4)*8,
// tid = (((t*4+bg)*8+kt)*4+nt)*64+lane.
__global__ void k_embed(const int* __restrict__ tok, const float* __restrict__ emb,
                        ushort* __restrict__ x2) {
  const int tid = blockIdx.x * 256 + threadIdx.x;   // 0..1048575
  const int lane = tid & 63;
  const int nt = (tid >> 6) & 3;
  const int kt = (tid >> 8) & 7;
  const int bg = (tid >> 11) & 3;
  const int t  = tid >> 13;
  const int b  = bg * 64 + nt * 16 + (lane & 15);
  const int e0 = kt * 32 + (lane >> 4) * 8;
  const int tk = tok[b * NT + t];
  const float4 v0 = *(const float4*)(emb + (size_t)tk * NE + e0);
  const float4 v1 = *(const float4*)(emb + (size_t)tk * NE + e0 + 4);
  ushort4 o0, o1;
  o0.x = f2bf(v0.x); o0.y = f2bf(v0.y); o0.z = f2bf(v0.z); o0.w = f2bf(v0.w);
  o1.x = f2bf(v1.x); o1.y = f2bf(v1.y); o1.z = f2bf(v1.z); o1.w = f2bf(v1.w);
  ushort4* dst = (ushort4*)(x2 + (size_t)tid * 8);
  dst[0] = o0; dst[1] = o1;
}

// ---------------- pack W^T / U^T into MFMA A-fragment order ----------------
// M-order within cg: ml = hdl*4 + g so the D-frag's 4 regs are the 4 gates
// of one h-dim. pack[chain][cg][kt][mt][lane][j].
__global__ void k_pack(const float* __restrict__ Wf, const float* __restrict__ Uf,
                       const float* __restrict__ Wb, const float* __restrict__ Ub,
                       ushort* __restrict__ wt, ushort* __restrict__ ut) {
  const int tid = blockIdx.x * 256 + threadIdx.x;   // 0..196607
  const int l = tid & 63;
  const int mt = (tid >> 6) & 7;
  const int kt = (tid >> 9) & 7;
  const int cg = (tid >> 12) & 7;
  const int chain = tid >> 15;                      // 0..5
  const int ll = chain >> 1, dir = chain & 1;
  const int ml = mt * 16 + (l & 15);
  const int hdl = ml >> 2, g = ml & 3;
  const int col = g * 256 + cg * 32 + hdl;
  const int k0 = kt * 32 + ((l >> 4) << 3);
  const float* W = (dir ? Wb : Wf) + (size_t)ll * NE * NG;
  const float* U = (dir ? Ub : Uf) + (size_t)ll * NH * NG;
  ushort vw[8], vu[8];
#pragma unroll
  for (int j = 0; j < 8; ++j) {
    vw[j] = f2bf(W[(size_t)(k0 + j) * NG + col]);
    vu[j] = f2bf(U[(size_t)(k0 + j) * NG + col]);
  }
  ushort4* dw = (ushort4*)(wt + (size_t)tid * 8);
  dw[0] = make_ushort4(vw[0], vw[1], vw[2], vw[3]);
  dw[1] = make_ushort4(vw[4], vw[5], vw[6], vw[7]);
  ushort4* du = (ushort4*)(ut + (size_t)tid * 8);
  du[0] = make_ushort4(vu[0], vu[1], vu[2], vu[3]);
  du[1] = make_ushort4(vu[4], vu[5], vu[6], vu[7]);
}

// ---------------- zero tags (graph-replay safe) ----------------
__global__ void k_init(uint* __restrict__ p) { p[threadIdx.x] = 0u; }

// ---------------- recurrent kernel: 96 WGs x 512 thr ----------------
// LDS: W dir0 0..64K | W dir1 64K..128K | poll flags @131072 (2 x 64B)
__global__ __launch_bounds__(512, 2) void k_lstm(
    const ushort* __restrict__ x2, const ushort* __restrict__ wt,
    const ushort* __restrict__ ut, const float* __restrict__ bf_,
    const float* __restrict__ bb_, ushort* __restrict__ hbuf,
    uint* __restrict__ tags, float* __restrict__ out) {
  __shared__ __align__(16) char smem[131200];

  const int bid = blockIdx.x;
  const int w = (bid & 7) * 12 + (bid >> 3);   // 96 = 8*12, bijective
  const int ll = w >> 5, rr_ = w & 31, cg = rr_ >> 2, bg = rr_ & 3;
  const int tx = threadIdx.x;
  const int wv = tx >> 6, lane = tx & 63;
  const int dir = wv >> 2, mq = wv & 3;
  const int chain = ll * 2 + dir;
  const int l15 = lane & 15, hi = lane >> 4;

  // ---- preload W^T both dirs -> LDS (128 KB linear) ----
#pragma unroll
  for (int d2 = 0; d2 < 2; ++d2) {
    const bf16x8* wsrc = (const bf16x8*)(wt + (size_t)((ll * 2 + d2) * 8 + cg) * 32768);
    bf16x8* wdst = (bf16x8*)(smem + d2 * 65536);
#pragma unroll
    for (int i = 0; i < 8; ++i) wdst[i * 512 + tx] = wsrc[i * 512 + tx];
  }
  // ---- preload U^T slice (this wave's mq: mt = mq*2+q) -> regs ----
  bf16x8 uf[8][2];
#pragma unroll
  for (int kt = 0; kt < 8; ++kt)
#pragma unroll
    for (int q = 0; q < 2; ++q)
      uf[kt][q] = *(const bf16x8*)(ut + ((size_t)((chain * 8 + cg) * 8 + kt) * 8 + mq * 2 + q) * 512 + lane * 8);

  // ---- bias: acc[q][nt] reg r = gate r of h-dim (mq*8+q*4+hi) ----
  const float* bias = (dir ? bb_ : bf_) + ll * NG;
  float bias_r[2][4];
#pragma unroll
  for (int q = 0; q < 2; ++q)
#pragma unroll
    for (int g = 0; g < 4; ++g)
      bias_r[q][g] = bias[g * 256 + cg * 32 + mq * 8 + q * 4 + hi];

  float c_[2][4], hm[2][4];
#pragma unroll
  for (int q = 0; q < 2; ++q)
#pragma unroll
    for (int nt = 0; nt < 4; ++nt) { c_[q][nt] = 0.f; hm[q][nt] = -1e30f; }

  const int grpi = chain * 4 + bg;                 // 0..23
  uint* tag_base = tags + grpi * 32;
  uint* tag_own  = tag_base + cg * 4 + mq;
  const uint* tag_poll = tag_base + (lane & 31);
  uint* lflag = (uint*)(smem + 131072 + dir * 64);
  u64* hb64 = (u64*)hbuf;
  const size_t pslice_us = ((size_t)(grpi * 8 + cg) * 4 + mq) * 512;  // producer slice (ushorts)

  if (tx < 2) *(volatile uint*)(smem + 131072 + tx * 64) = 0u;
  __syncthreads();   // W LDS + flags ready (only barrier in the kernel)

  for (int tau = 0; tau < NT; ++tau) {
    const int t = dir ? (NT - 1 - tau) : tau;
    const ushort* xb_base = x2 + ((size_t)((t * 4 + bg) * 8) * 4) * 512;  // [kt][nt] frags follow

    f32x4 acc[2][4];
#pragma unroll
    for (int q = 0; q < 2; ++q)
#pragma unroll
      for (int nt = 0; nt < 4; ++nt)
        acc[q][nt] = (f32x4){bias_r[q][0], bias_r[q][1], bias_r[q][2], bias_r[q][3]};

    // ---- W.x kt0-3 (no sibling dependency; covers sibling tag flight) ----
#pragma unroll
    for (int kt = 0; kt < 4; ++kt) {
      bf16x8 xbv[4];
#pragma unroll
      for (int nt = 0; nt < 4; ++nt)
        xbv[nt] = *(const bf16x8*)(xb_base + ((size_t)(kt * 4 + nt) * 64 + lane) * 8);
#pragma unroll
      for (int q = 0; q < 2; ++q) {
        const bf16x8 wA = *(const bf16x8*)(smem + dir * 65536 + ((kt * 8 + mq * 2 + q) * 64 + lane) * 16);
#pragma unroll
        for (int nt = 0; nt < 4; ++nt)
          acc[q][nt] = __builtin_amdgcn_mfma_f32_16x16x32_bf16(wA, xbv[nt], acc[q][nt], 0, 0, 0);
      }
    }

    // ---- readiness: mq0 polls global tags; mq1-3 spin on LDS flag ----
    if (tau > 0) {
      if (mq == 0) {
        while (!__all(__hip_atomic_load(tag_poll, __ATOMIC_RELAXED, __HIP_MEMORY_SCOPE_AGENT) >= (uint)tau))
          __builtin_amdgcn_s_sleep(1);
        if (lane == 0)
          __hip_atomic_store(lflag, (uint)tau, __ATOMIC_RELAXED, __HIP_MEMORY_SCOPE_WORKGROUP);
      } else {
        while (__hip_atomic_load(lflag, __ATOMIC_RELAXED, __HIP_MEMORY_SCOPE_WORKGROUP) < (uint)tau)
          __builtin_amdgcn_s_sleep(1);
      }
      asm volatile("" ::: "memory");
    }

    // ---- hq group A: kt0-2 (issued under W.x kt4-7) ----
    u64 hqa[24], hqb[24], hqc[16];
    const u64* hs = hb64 + (size_t)((tau - 1) & 1) * HB_PAR_U64;
    if (tau > 0) {
#pragma unroll
      for (int kt = 0; kt < 3; ++kt) {
        const u64* sp = hs + ((size_t)(grpi * 8 + kt) * 4 + hi) * 128 + l15 * 2;
#pragma unroll
        for (int nt = 0; nt < 4; ++nt) {
          hqa[kt * 8 + nt * 2]     = __hip_atomic_load(sp + nt * 32,     __ATOMIC_RELAXED, __HIP_MEMORY_SCOPE_AGENT);
          hqa[kt * 8 + nt * 2 + 1] = __hip_atomic_load(sp + nt * 32 + 1, __ATOMIC_RELAXED, __HIP_MEMORY_SCOPE_AGENT);
        }
      }
    }

    // ---- W.x kt4-7 ----
#pragma unroll
    for (int kt = 4; kt < 8; ++kt) {
      bf16x8 xbv[4];
#pragma unroll
      for (int nt = 0; nt < 4; ++nt)
        xbv[nt] = *(const bf16x8*)(xb_base + ((size_t)(kt * 4 + nt) * 64 + lane) * 8);
#pragma unroll
      for (int q = 0; q < 2; ++q) {
        const bf16x8 wA = *(const bf16x8*)(smem + dir * 65536 + ((kt * 8 + mq * 2 + q) * 64 + lane) * 16);
#pragma unroll
        for (int nt = 0; nt < 4; ++nt)
          acc[q][nt] = __builtin_amdgcn_mfma_f32_16x16x32_bf16(wA, xbv[nt], acc[q][nt], 0, 0, 0);
      }
    }

    if (tau > 0) {
      // ---- hq group B: kt3-5 ----
#pragma unroll
      for (int kt = 3; kt < 6; ++kt) {
        const u64* sp = hs + ((size_t)(grpi * 8 + kt) * 4 + hi) * 128 + l15 * 2;
#pragma unroll
        for (int nt = 0; nt < 4; ++nt) {
          hqb[(kt - 3) * 8 + nt * 2]     = __hip_atomic_load(sp + nt * 32,     __ATOMIC_RELAXED, __HIP_MEMORY_SCOPE_AGENT);
          hqb[(kt - 3) * 8 + nt * 2 + 1] = __hip_atomic_load(sp + nt * 32 + 1, __ATOMIC_RELAXED, __HIP_MEMORY_SCOPE_AGENT);
        }
      }
      // ---- U.h kt0-2 ----
#pragma unroll
      for (int kt = 0; kt < 3; ++kt)
#pragma unroll
        for (int nt = 0; nt < 4; ++nt) {
          union { u64 qq[2]; bf16x8 v; } u;
          u.qq[0] = hqa[kt * 8 + nt * 2]; u.qq[1] = hqa[kt * 8 + nt * 2 + 1];
#pragma unroll
          for (int q = 0; q < 2; ++q)
            acc[q][nt] = __builtin_amdgcn_mfma_f32_16x16x32_bf16(uf[kt][q], u.v, acc[q][nt], 0, 0, 0);
        }
      // ---- hq group C: kt6-7 ----
#pragma unroll
      for (int kt = 6; kt < 8; ++kt) {
        const u64* sp = hs + ((size_t)(grpi * 8 + kt) * 4 + hi) * 128 + l15 * 2;
#pragma unroll
        for (int nt = 0; nt < 4; ++nt) {
          hqc[(kt - 6) * 8 + nt * 2]     = __hip_atomic_load(sp + nt * 32,     __ATOMIC_RELAXED, __HIP_MEMORY_SCOPE_AGENT);
          hqc[(kt - 6) * 8 + nt * 2 + 1] = __hip_atomic_load(sp + nt * 32 + 1, __ATOMIC_RELAXED, __HIP_MEMORY_SCOPE_AGENT);
        }
      }
      // ---- U.h kt3-5 ----
#pragma unroll
      for (int kt = 3; kt < 6; ++kt)
#pragma unroll
        for (int nt = 0; nt < 4; ++nt) {
          union { u64 qq[2]; bf16x8 v; } u;
          u.qq[0] = hqb[(kt - 3) * 8 + nt * 2]; u.qq[1] = hqb[(kt - 3) * 8 + nt * 2 + 1];
#pragma unroll
          for (int q = 0; q < 2; ++q)
            acc[q][nt] = __builtin_amdgcn_mfma_f32_16x16x32_bf16(uf[kt][q], u.v, acc[q][nt], 0, 0, 0);
        }
      // ---- U.h kt6-7 ----
#pragma unroll
      for (int kt = 6; kt < 8; ++kt)
#pragma unroll
        for (int nt = 0; nt < 4; ++nt) {
          union { u64 qq[2]; bf16x8 v; } u;
          u.qq[0] = hqc[(kt - 6) * 8 + nt * 2]; u.qq[1] = hqc[(kt - 6) * 8 + nt * 2 + 1];
#pragma unroll
          for (int q = 0; q < 2; ++q)
            acc[q][nt] = __builtin_amdgcn_mfma_f32_16x16x32_bf16(uf[kt][q], u.v, acc[q][nt], 0, 0, 0);
        }
    }

    // ---- gates + direct scattered publish (self-contained wave slice) ----
    ushort* pw = hbuf + (size_t)(tau & 1) * HB_PAR_US + pslice_us;
    const bool dopub = (tau + 1 < NT);
#pragma unroll
    for (int q = 0; q < 2; ++q)
#pragma unroll
      for (int nt = 0; nt < 4; ++nt) {
        const float iv = sigf(acc[q][nt][0]);
        const float fv = sigf(acc[q][nt][1]);
        const float gv = tanhf_(acc[q][nt][2]);
        const float ov = sigf(acc[q][nt][3]);
        const float cn = fv * c_[q][nt] + iv * gv;
        c_[q][nt] = cn;
        const float hv = ov * tanhf_(cn);
        hm[q][nt] = fmaxf(hm[q][nt], hv);
        if (dopub)
          __hip_atomic_store(pw + nt * 128 + l15 * 8 + q * 4 + hi, f2bf(hv),
                             __ATOMIC_RELAXED, __HIP_MEMORY_SCOPE_AGENT);
      }
    if (dopub) {
      asm volatile("s_waitcnt vmcnt(0)" ::: "memory");   // h_tau at coherence point
      if (lane == 0)
        __hip_atomic_store(tag_own, (uint)(tau + 1), __ATOMIC_RELAXED, __HIP_MEMORY_SCOPE_AGENT);
    }
  }

  // ---- maxpool output ----
#pragma unroll
  for (int q = 0; q < 2; ++q)
#pragma unroll
    for (int nt = 0; nt < 4; ++nt) {
      const int b = bg * 64 + nt * 16 + l15;
      const int col = ll * 512 + dir * 256 + cg * 32 + mq * 8 + q * 4 + hi;
      out[(size_t)b * 1536 + col] = hm[q][nt];
    }
}

extern "C" void kernel_launch(void* const* d_in, const int* in_sizes, int n_in,
                              void* d_out, int out_size, void* d_ws, size_t ws_size,
                              hipStream_t stream) {
  (void)in_sizes; (void)n_in; (void)out_size; (void)ws_size;
  const int*   tokens = (const int*)d_in[0];
  const float* Emb    = (const float*)d_in[1];
  const float* Wf     = (const float*)d_in[2];
  const float* Uf     = (const float*)d_in[3];
  const float* bf_    = (const float*)d_in[4];
  const float* Wb     = (const float*)d_in[5];
  const float* Ub     = (const float*)d_in[6];
  const float* bb_    = (const float*)d_in[7];
  float* out = (float*)d_out;

  ushort* x2   = (ushort*)((char*)d_ws + X_OFF);
  ushort* wt   = (ushort*)((char*)d_ws + WT_OFF);
  ushort* ut   = (ushort*)((char*)d_ws + UT_OFF);
  ushort* hbuf = (ushort*)((char*)d_ws + HB_OFF);
  uint*   tags = (uint*)((char*)d_ws + TAG_OFF);

  hipLaunchKernelGGL(k_embed, dim3(4096), dim3(256), 0, stream, tokens, Emb, x2);
  hipLaunchKernelGGL(k_pack, dim3(768), dim3(256), 0, stream, Wf, Uf, Wb, Ub, wt, ut);
  hipLaunchKernelGGL(k_init, dim3(1), dim3(768), 0, stream, tags);
  hipLaunchKernelGGL(k_lstm, dim3(96), dim3(512), 0, stream, x2, wt, ut, bf_, bb_, hbuf, tags, out);
}